// Round 5
// baseline (239.062 us; speedup 1.0000x reference)
//
#include <hip/hip_runtime.h>
#include <hip/hip_bf16.h>
#include <math.h>

#define B_ 2
#define N_ 4096          // H*W*D
#define BN_ 8192
#define NH_ 4
#define SPLIT_ 4         // attention K-split

using bf16x8   = __attribute__((ext_vector_type(8))) __bf16;
using f32x4    = __attribute__((ext_vector_type(4))) float;
using ushortx8 = __attribute__((ext_vector_type(8))) unsigned short;

#if __has_builtin(__builtin_amdgcn_exp2f)
#define FAST_EXP2(x) __builtin_amdgcn_exp2f(x)
#else
#define FAST_EXP2(x) __expf((x) * 0.6931471805599453f)
#endif

static __device__ __forceinline__ unsigned short f2bf(float f) {
    union { __hip_bfloat16 h; unsigned short u; } c;
    c.h = __float2bfloat16(f);
    return c.u;
}
static __device__ __forceinline__ float bf2f(unsigned short u) {
    union { __hip_bfloat16 h; unsigned short u; } c;
    c.u = u;
    return __bfloat162float(c.h);
}
// pack two f32 -> two bf16 (round-biased truncate) in one v_perm_b32
static __device__ __forceinline__ unsigned int pk2bf(float lo, float hi) {
    return __builtin_amdgcn_perm(__float_as_uint(hi) + 0x8000u,
                                 __float_as_uint(lo) + 0x8000u, 0x07060302u);
}

// ---------------------------------------------------------------------------
// Convert all six weight matrices fp32 -> bf16.
// ---------------------------------------------------------------------------
__global__ __launch_bounds__(256)
void convert_weights_kernel(const float* __restrict__ Wq, const float* __restrict__ Wk,
                            const float* __restrict__ Wv, const float* __restrict__ Wo,
                            const float* __restrict__ W1, const float* __restrict__ W2,
                            unsigned short* __restrict__ wq, unsigned short* __restrict__ wk,
                            unsigned short* __restrict__ wv, unsigned short* __restrict__ wo,
                            unsigned short* __restrict__ w1, unsigned short* __restrict__ w2) {
    const int id = blockIdx.x * 256 + threadIdx.x;
    if      (id <  16384) wq[id]          = f2bf(Wq[id]);
    else if (id <  32768) wk[id - 16384]  = f2bf(Wk[id - 16384]);
    else if (id <  49152) wv[id - 32768]  = f2bf(Wv[id - 32768]);
    else if (id <  65536) wo[id - 49152]  = f2bf(Wo[id - 49152]);
    else if (id < 131072) w1[id - 65536]  = f2bf(W1[id - 65536]);
    else                  w2[id - 131072] = f2bf(W2[id - 131072]);
}

// ---------------------------------------------------------------------------
// LayerNorm + transpose (enc & dec merged): fp32 [B,C,N] -> bf16 [B*N, C].
// Grid (N/32, B, 2): z=0 -> enc, z=1 -> dec.
// ---------------------------------------------------------------------------
__global__ __launch_bounds__(256)
void ln_transpose_kernel(const float* __restrict__ enc, const float* __restrict__ dec,
                         const float* __restrict__ g_enc, const float* __restrict__ b_enc,
                         const float* __restrict__ g_dec, const float* __restrict__ b_dec,
                         unsigned short* __restrict__ enc_out,
                         unsigned short* __restrict__ dec_out) {
    __shared__ float tile[128][33];
    __shared__ float mu_s[32], inv_s[32];
    const int z  = blockIdx.z;
    const float* in     = z ? dec   : enc;
    const float* gamma  = z ? g_dec : g_enc;
    const float* beta   = z ? b_dec : b_enc;
    unsigned short* outb = z ? dec_out : enc_out;
    const int b  = blockIdx.y;
    const int n0 = blockIdx.x * 32;
    const int t  = threadIdx.x;
    const float* inb = in + (size_t)b * 128 * N_;

    {
        const int col = t & 31;
        const int r0  = t >> 5;
        for (int j = 0; j < 16; ++j) {
            const int r = r0 + 8 * j;
            tile[r][col] = inb[(size_t)r * N_ + n0 + col];
        }
    }
    __syncthreads();
    {
        const int tok = t >> 3;
        const int ln  = t & 7;
        float s = 0.f, ss = 0.f;
        for (int c = ln; c < 128; c += 8) {
            const float x = tile[c][tok];
            s += x; ss += x * x;
        }
        for (int m = 1; m < 8; m <<= 1) {
            s  += __shfl_xor(s, m);
            ss += __shfl_xor(ss, m);
        }
        if (ln == 0) {
            const float mu  = s * (1.f / 128.f);
            const float var = ss * (1.f / 128.f) - mu * mu;
            mu_s[tok]  = mu;
            inv_s[tok] = rsqrtf(var + 1e-5f);
        }
    }
    __syncthreads();
    const size_t obase = ((size_t)b * N_ + n0) * 128;
    for (int j = 0; j < 16; ++j) {
        const int f  = t + 256 * j;
        const int tk = f >> 7;
        const int c  = f & 127;
        const float x = tile[c][tk];
        outb[obase + f] = f2bf((x - mu_s[tk]) * inv_s[tk] * gamma[c] + beta[c]);
    }
}

// ---------------------------------------------------------------------------
// QKV projection, bf16 MFMA, no LDS. Q is pre-scaled by (1/sqrt(d))*log2(e)
// so attention can use raw exp2. V written pre-transposed [bh, 32, n].
// ---------------------------------------------------------------------------
__global__ __launch_bounds__(128)
void qkv_gemm_kernel(const unsigned short* __restrict__ decb,
                     const unsigned short* __restrict__ encb,
                     const unsigned short* __restrict__ wq,
                     const unsigned short* __restrict__ wk,
                     const unsigned short* __restrict__ wv,
                     const float* __restrict__ bq, const float* __restrict__ bk,
                     const float* __restrict__ bv,
                     unsigned short* __restrict__ Qh, unsigned short* __restrict__ Kh,
                     unsigned short* __restrict__ Vt) {
    const int z = blockIdx.y;
    const int t = threadIdx.x;
    const int wvx = t >> 6, lane = t & 63;
    const int l15 = lane & 15, quad = lane >> 4;
    const int m0 = blockIdx.x * 32 + wvx * 16;
    const unsigned short* X    = (z == 0) ? decb : encb;
    const unsigned short* Wb   = (z == 0) ? wq : (z == 1) ? wk : wv;
    const float*          bias = (z == 0) ? bq : (z == 1) ? bk : bv;

    bf16x8 af[4];
    #pragma unroll
    for (int kk = 0; kk < 4; ++kk)
        af[kk] = *(const bf16x8*)(X + (size_t)(m0 + l15) * 128 + kk * 32 + quad * 8);

    f32x4 acc[8];
    #pragma unroll
    for (int nb = 0; nb < 8; ++nb) {
        f32x4 a = {0.f, 0.f, 0.f, 0.f};
        #pragma unroll
        for (int kk = 0; kk < 4; ++kk) {
            const bf16x8 wf = *(const bf16x8*)(Wb + (size_t)(nb * 16 + l15) * 128 + kk * 32 + quad * 8);
            a = __builtin_amdgcn_mfma_f32_16x16x32_bf16(af[kk], wf, a, 0, 0, 0);
        }
        acc[nb] = a;
    }

    const float qsc = 0.17677669529663687f * 1.4426950408889634f;  // 1/sqrt(32)*log2e
    const int b   = m0 >> 12;
    const int nb0 = (m0 & 4095) + quad * 4;
    #pragma unroll
    for (int nb = 0; nb < 8; ++nb) {
        const int col = nb * 16 + l15;
        const int h = col >> 5, d = col & 31;
        const float bz = bias[col];
        if (z == 2) {
            ushort4 pk;
            pk.x = f2bf(acc[nb][0] + bz);
            pk.y = f2bf(acc[nb][1] + bz);
            pk.z = f2bf(acc[nb][2] + bz);
            pk.w = f2bf(acc[nb][3] + bz);
            *(ushort4*)(Vt + ((size_t)(b * NH_ + h) * 32 + d) * N_ + nb0) = pk;
        } else {
            unsigned short* dst = (z == 0) ? Qh : Kh;
            const float sc = (z == 0) ? qsc : 1.f;
            #pragma unroll
            for (int r = 0; r < 4; ++r) {
                const int n = nb0 + r;
                dst[((size_t)(b * NH_ + h) * N_ + n) * 32 + d] = f2bf((acc[nb][r] + bz) * sc);
            }
        }
    }
}

// ---------------------------------------------------------------------------
// Split-K MFMA flash attention, SPLIT=4, base-2 max-free softmax.
// SOFTWARE-PIPELINED: V tiles for the current chunk and K tiles for the NEXT
// chunk are issued at the top of each iteration, so all 8 global loads are in
// flight behind the S^T/exp/LDS work. No barriers (sP is wave-private).
// Grid (N/64, NH, B*SPLIT).
// ---------------------------------------------------------------------------
__global__ __launch_bounds__(256)
void attn_kernel4(const unsigned short* __restrict__ Qh,
                  const unsigned short* __restrict__ Kh,
                  const unsigned short* __restrict__ Vt,
                  unsigned short* __restrict__ Op,
                  unsigned short* __restrict__ lp) {
    __shared__ alignas(16) unsigned short sP[4][16][72];  // wave-private, stride 72

    const int b  = blockIdx.z >> 2;
    const int s  = blockIdx.z & 3;
    const int h  = blockIdx.y;
    const int q0 = blockIdx.x * 64;
    const int t  = threadIdx.x;
    const int wvx = t >> 6, lane = t & 63;
    const int l15 = lane & 15, quad = lane >> 4;
    const int bh = b * NH_ + h;
    const size_t hbse = (size_t)bh * N_ * 32;

    const bf16x8 qf = *(const bf16x8*)(Qh + hbse + (size_t)(q0 + wvx * 16 + l15) * 32 + quad * 8);
    const unsigned short* Kp = Kh + hbse;
    const unsigned short* Vp = Vt + (size_t)bh * 32 * N_;

    f32x4 o0 = {0.f, 0.f, 0.f, 0.f};
    f32x4 o1 = {0.f, 0.f, 0.f, 0.f};
    float l = 0.f;
    const f32x4 zero = {0.f, 0.f, 0.f, 0.f};

    const int kbeg = s * (N_ / SPLIT_);
    const int kend = kbeg + (N_ / SPLIT_);

    // prefetch first chunk's K tiles
    bf16x8 kf[4];
    #pragma unroll
    for (int c = 0; c < 4; ++c)
        kf[c] = *(const bf16x8*)(Kp + (size_t)(kbeg + c * 16 + l15) * 32 + quad * 8);

    for (int k0 = kbeg; k0 < kend; k0 += 64) {
        // issue V loads for CURRENT chunk (consumed after the S^T phase)
        bf16x8 va[2], vb[2];
        #pragma unroll
        for (int s2 = 0; s2 < 2; ++s2) {
            va[s2] = *(const bf16x8*)(Vp + (size_t)l15 * N_        + k0 + s2 * 32 + quad * 8);
            vb[s2] = *(const bf16x8*)(Vp + (size_t)(16 + l15) * N_ + k0 + s2 * 32 + quad * 8);
        }
        // issue K loads for NEXT chunk (consumed a full iteration later)
        const int kn = (k0 + 64 < kend) ? (k0 + 64) : kbeg;
        bf16x8 kfn[4];
        #pragma unroll
        for (int c = 0; c < 4; ++c)
            kfn[c] = *(const bf16x8*)(Kp + (size_t)(kn + c * 16 + l15) * 32 + quad * 8);

        // S^T = mfma(K, Q) from the prefetched kf
        #pragma unroll
        for (int c = 0; c < 4; ++c) {
            const f32x4 sv = __builtin_amdgcn_mfma_f32_16x16x32_bf16(kf[c], qf, zero, 0, 0, 0);
            const float p0 = FAST_EXP2(sv[0]);
            const float p1 = FAST_EXP2(sv[1]);
            const float p2 = FAST_EXP2(sv[2]);
            const float p3 = FAST_EXP2(sv[3]);
            l += (p0 + p1) + (p2 + p3);
            uint2 pk;
            pk.x = pk2bf(p0, p1);
            pk.y = pk2bf(p2, p3);
            *(uint2*)&sP[wvx][l15][c * 16 + quad * 4] = pk;
        }
        // PV: V arrived during S^T
        #pragma unroll
        for (int s2 = 0; s2 < 2; ++s2) {
            const bf16x8 pf = *(const bf16x8*)&sP[wvx][l15][s2 * 32 + quad * 8];
            o0 = __builtin_amdgcn_mfma_f32_16x16x32_bf16(va[s2], pf, o0, 0, 0, 0);
            o1 = __builtin_amdgcn_mfma_f32_16x16x32_bf16(vb[s2], pf, o1, 0, 0, 0);
        }
        #pragma unroll
        for (int c = 0; c < 4; ++c) kf[c] = kfn[c];
    }

    l += __shfl_xor(l, 16);
    l += __shfl_xor(l, 32);

    const size_t ob = ((size_t)(s * 8 + bh) * N_ + q0 + wvx * 16 + l15) * 32;
    uint2 w0, w1v;
    w0.x  = pk2bf(o0[0], o0[1]); w0.y  = pk2bf(o0[2], o0[3]);
    w1v.x = pk2bf(o1[0], o1[1]); w1v.y = pk2bf(o1[2], o1[3]);
    *(uint2*)&Op[ob + quad * 4]      = w0;
    *(uint2*)&Op[ob + 16 + quad * 4] = w1v;
    if (quad == 0)
        lp[(size_t)(s * 8 + bh) * N_ + q0 + wvx * 16 + l15] = f2bf(l);
}

// ---------------------------------------------------------------------------
// Combine split-K partials: ctx = (sum_s Op)/(sum_s l), bf16 out.
// ---------------------------------------------------------------------------
__global__ __launch_bounds__(256)
void combine_kernel(const unsigned short* __restrict__ Op,
                    const unsigned short* __restrict__ lp,
                    unsigned short* __restrict__ ctx) {
    const int gid = blockIdx.x * 256 + threadIdx.x;   // 0 .. 131071
    const int token = gid >> 4;
    const int c8 = gid & 15;
    const int b = token >> 12, n = token & 4095;
    const int h = c8 >> 2;
    const int d0 = (c8 & 3) * 8;
    const int bh = b * NH_ + h;

    f32x4 sa = {0.f, 0.f, 0.f, 0.f}, sb = {0.f, 0.f, 0.f, 0.f};
    float lt = 0.f;
    #pragma unroll
    for (int s = 0; s < SPLIT_; ++s) {
        const size_t base = ((size_t)(s * 8 + bh) * N_ + n) * 32 + d0;
        const ushortx8 u = *(const ushortx8*)&Op[base];
        sa[0] += bf2f(u[0]); sa[1] += bf2f(u[1]);
        sa[2] += bf2f(u[2]); sa[3] += bf2f(u[3]);
        sb[0] += bf2f(u[4]); sb[1] += bf2f(u[5]);
        sb[2] += bf2f(u[6]); sb[3] += bf2f(u[7]);
        lt += bf2f(lp[(size_t)(s * 8 + bh) * N_ + n]);
    }
    const float inv = 1.f / lt;
    uint4 pk;
    pk.x = pk2bf(sa[0] * inv, sa[1] * inv);
    pk.y = pk2bf(sa[2] * inv, sa[3] * inv);
    pk.z = pk2bf(sb[0] * inv, sb[1] * inv);
    pk.w = pk2bf(sb[2] * inv, sb[3] * inv);
    *(uint4*)(ctx + (size_t)token * 128 + c8 * 8) = pk;
}

// ---------------------------------------------------------------------------
// Wo projection + residual + fused full-row LayerNorm. 4 waves/block:
// 2 token-tiles x 2 K-halves; LDS reduce; kh==0 waves run the epilogue.
// ---------------------------------------------------------------------------
__global__ __launch_bounds__(256)
void wo_gemm_kernel(const unsigned short* __restrict__ ctx,
                    const unsigned short* __restrict__ wo,
                    const float* __restrict__ bo,
                    const unsigned short* __restrict__ decb,
                    const float* __restrict__ g, const float* __restrict__ be,
                    unsigned short* __restrict__ out1,
                    unsigned short* __restrict__ hb) {
    __shared__ alignas(16) float sred[2][64][32];   // 16 KB
    const int t = threadIdx.x;
    const int wvx = t >> 6, lane = t & 63;
    const int pair = wvx >> 1, kh = wvx & 1;
    const int l15 = lane & 15, quad = lane >> 4;
    const int m0 = blockIdx.x * 32 + pair * 16;

    bf16x8 af[2];
    #pragma unroll
    for (int kk = 0; kk < 2; ++kk)
        af[kk] = *(const bf16x8*)(ctx + (size_t)(m0 + l15) * 128 + (kh * 2 + kk) * 32 + quad * 8);

    float v[8][4];
    #pragma unroll
    for (int nb = 0; nb < 8; ++nb) {
        f32x4 a = {0.f, 0.f, 0.f, 0.f};
        #pragma unroll
        for (int kk = 0; kk < 2; ++kk) {
            const bf16x8 wf = *(const bf16x8*)(wo + (size_t)(nb * 16 + l15) * 128 + (kh * 2 + kk) * 32 + quad * 8);
            a = __builtin_amdgcn_mfma_f32_16x16x32_bf16(af[kk], wf, a, 0, 0, 0);
        }
        #pragma unroll
        for (int r = 0; r < 4; ++r) v[nb][r] = a[r];
    }

    if (kh == 1) {
        #pragma unroll
        for (int nb = 0; nb < 8; ++nb)
            *(f32x4*)&sred[pair][lane][nb * 4] = *(f32x4*)&v[nb][0];
    }
    __syncthreads();
    if (kh == 0) {
        #pragma unroll
        for (int nb = 0; nb < 8; ++nb) {
            const f32x4 p = *(const f32x4*)&sred[pair][lane][nb * 4];
            const int col = nb * 16 + l15;
            const float bz = bo[col];
            #pragma unroll
            for (int r = 0; r < 4; ++r) {
                const int tok = m0 + quad * 4 + r;
                v[nb][r] += p[r] + bz + bf2f(decb[(size_t)tok * 128 + col]);
            }
        }
        float mu[4], inv[4];
        #pragma unroll
        for (int r = 0; r < 4; ++r) {
            float s = 0.f, ss = 0.f;
            #pragma unroll
            for (int nb = 0; nb < 8; ++nb) { s += v[nb][r]; ss += v[nb][r] * v[nb][r]; }
            for (int m = 1; m < 16; m <<= 1) {
                s  += __shfl_xor(s, m);
                ss += __shfl_xor(ss, m);
            }
            mu[r] = s * (1.f / 128.f);
            inv[r] = rsqrtf(ss * (1.f / 128.f) - mu[r] * mu[r] + 1e-5f);
        }
        #pragma unroll
        for (int nb = 0; nb < 8; ++nb) {
            const int col = nb * 16 + l15;
            const float gg = g[col], bb2 = be[col];
            #pragma unroll
            for (int r = 0; r < 4; ++r) {
                const int tok = m0 + quad * 4 + r;
                out1[(size_t)tok * 128 + col] = f2bf(v[nb][r]);
                hb[(size_t)tok * 128 + col]   = f2bf((v[nb][r] - mu[r]) * inv[r] * gg + bb2);
            }
        }
    }
}

// ---------------------------------------------------------------------------
// FFN1: mid = gelu(hb @ W1^T + b1), bf16 [BN, 512]. Grid (BN/32, 4).
// ---------------------------------------------------------------------------
__global__ __launch_bounds__(128)
void ffn1_kernel(const unsigned short* __restrict__ hb,
                 const unsigned short* __restrict__ w1,
                 const float* __restrict__ b1,
                 unsigned short* __restrict__ midb) {
    const int t = threadIdx.x;
    const int wvx = t >> 6, lane = t & 63;
    const int l15 = lane & 15, quad = lane >> 4;
    const int m0 = blockIdx.x * 32 + wvx * 16;
    const int nbase = blockIdx.y * 128;

    bf16x8 af[4];
    #pragma unroll
    for (int kk = 0; kk < 4; ++kk)
        af[kk] = *(const bf16x8*)(hb + (size_t)(m0 + l15) * 128 + kk * 32 + quad * 8);

    #pragma unroll
    for (int nb = 0; nb < 8; ++nb) {
        f32x4 a = {0.f, 0.f, 0.f, 0.f};
        const int col = nbase + nb * 16 + l15;
        #pragma unroll
        for (int kk = 0; kk < 4; ++kk) {
            const bf16x8 wf = *(const bf16x8*)(w1 + (size_t)col * 128 + kk * 32 + quad * 8);
            a = __builtin_amdgcn_mfma_f32_16x16x32_bf16(af[kk], wf, a, 0, 0, 0);
        }
        const float bz = b1[col];
        #pragma unroll
        for (int r = 0; r < 4; ++r) {
            const int tok = m0 + quad * 4 + r;
            float x = a[r] + bz;
            x = 0.5f * x * (1.f + erff(x * 0.70710678118f));
            midb[(size_t)tok * 512 + col] = f2bf(x);
        }
    }
}

// ---------------------------------------------------------------------------
// FFN2: final = mid @ W2^T + b2 + out1 -> [B,128,N] fp32. 4 waves/block:
// 2 token-tiles x 2 K-halves (K=512); LDS reduce; kh==0 epilogue.
// ---------------------------------------------------------------------------
__global__ __launch_bounds__(256)
void ffn2_kernel(const unsigned short* __restrict__ midb,
                 const unsigned short* __restrict__ w2,
                 const float* __restrict__ b2,
                 const unsigned short* __restrict__ out1,
                 float* __restrict__ out) {
    __shared__ alignas(16) float sred[2][64][32];   // 16 KB
    const int t = threadIdx.x;
    const int wvx = t >> 6, lane = t & 63;
    const int pair = wvx >> 1, kh = wvx & 1;
    const int l15 = lane & 15, quad = lane >> 4;
    const int m0 = blockIdx.x * 32 + pair * 16;

    bf16x8 af[8];
    #pragma unroll
    for (int kk = 0; kk < 8; ++kk)
        af[kk] = *(const bf16x8*)(midb + (size_t)(m0 + l15) * 512 + (kh * 8 + kk) * 32 + quad * 8);

    float v[8][4];
    #pragma unroll
    for (int nb = 0; nb < 8; ++nb) {
        f32x4 a = {0.f, 0.f, 0.f, 0.f};
        const int col = nb * 16 + l15;
        #pragma unroll
        for (int kk = 0; kk < 8; ++kk) {
            const bf16x8 wf = *(const bf16x8*)(w2 + (size_t)col * 512 + (kh * 8 + kk) * 32 + quad * 8);
            a = __builtin_amdgcn_mfma_f32_16x16x32_bf16(af[kk], wf, a, 0, 0, 0);
        }
        #pragma unroll
        for (int r = 0; r < 4; ++r) v[nb][r] = a[r];
    }

    if (kh == 1) {
        #pragma unroll
        for (int nb = 0; nb < 8; ++nb)
            *(f32x4*)&sred[pair][lane][nb * 4] = *(f32x4*)&v[nb][0];
    }
    __syncthreads();
    if (kh == 0) {
        const int b = m0 >> 12;
        const int nb0 = (m0 & 4095) + quad * 4;
        #pragma unroll
        for (int nb = 0; nb < 8; ++nb) {
            const f32x4 p = *(const f32x4*)&sred[pair][lane][nb * 4];
            const int col = nb * 16 + l15;
            const float bz = b2[col];
            f32x4 res;
            #pragma unroll
            for (int r = 0; r < 4; ++r) {
                const int tok = m0 + quad * 4 + r;
                res[r] = v[nb][r] + p[r] + bz + bf2f(out1[(size_t)tok * 128 + col]);
            }
            *(f32x4*)&out[((size_t)(b * 128 + col)) * N_ + nb0] = res;
        }
    }
}

// ---------------------------------------------------------------------------
extern "C" void kernel_launch(void* const* d_in, const int* in_sizes, int n_in,
                              void* d_out, int out_size, void* d_ws, size_t ws_size,
                              hipStream_t stream) {
    const float* enc   = (const float*)d_in[0];
    const float* dec   = (const float*)d_in[1];
    const float* Wq    = (const float*)d_in[2];
    const float* bq    = (const float*)d_in[3];
    const float* Wk    = (const float*)d_in[4];
    const float* bk    = (const float*)d_in[5];
    const float* Wv    = (const float*)d_in[6];
    const float* bv    = (const float*)d_in[7];
    const float* Wo    = (const float*)d_in[8];
    const float* bo    = (const float*)d_in[9];
    const float* g_enc = (const float*)d_in[10];
    const float* b_enc = (const float*)d_in[11];
    const float* g_dec = (const float*)d_in[12];
    const float* b_dec = (const float*)d_in[13];
    const float* g_out = (const float*)d_in[14];
    const float* b_out = (const float*)d_in[15];
    const float* W1    = (const float*)d_in[16];
    const float* b1    = (const float*)d_in[17];
    const float* W2    = (const float*)d_in[18];
    const float* b2    = (const float*)d_in[19];
    float* out = (float*)d_out;
    char*  W   = (char*)d_ws;

    // workspace layout (same 27 MB footprint as R3/R4 which passed)
    unsigned short* wqb = (unsigned short*)(W);
    unsigned short* wkb = wqb + 16384;
    unsigned short* wvb = wkb + 16384;
    unsigned short* wob = wvb + 16384;
    unsigned short* w1b = wob + 16384;
    unsigned short* w2b = w1b + 65536;                                  // ends 384 KB
    unsigned short* enc_lnb = (unsigned short*)(W + (512ull  << 10));   // [0.5, 2.5) MB
    unsigned short* dec_lnb = (unsigned short*)(W + (2560ull << 10));   // [2.5, 4.5)
    unsigned short* Qh      = (unsigned short*)(W + (4608ull << 10));   // [4.5, 6.5)
    unsigned short* Kh      = (unsigned short*)(W + (6656ull << 10));   // [6.5, 8.5)
    unsigned short* Vt      = (unsigned short*)(W + (8704ull << 10));   // [8.5, 10.5)
    unsigned short* Op      = (unsigned short*)(W + (10752ull << 10));  // 8 MB (SPLIT=4)
    unsigned short* lpb     = (unsigned short*)(W + (27136ull << 10));  // [26.5, 27)
    unsigned short* ctx  = enc_lnb;                 // overlay (enc dead after QKV)
    unsigned short* out1 = Qh;                      // overlay (Q dead after attn)
    unsigned short* hbuf = Kh;                      // overlay (K dead after attn)
    unsigned short* midb = Op;                      // overlay (Op dead after combine)

    convert_weights_kernel<<<768, 256, 0, stream>>>(Wq, Wk, Wv, Wo, W1, W2,
                                                    wqb, wkb, wvb, wob, w1b, w2b);

    ln_transpose_kernel<<<dim3(N_ / 32, B_, 2), 256, 0, stream>>>(
        enc, dec, g_enc, b_enc, g_dec, b_dec, enc_lnb, dec_lnb);

    qkv_gemm_kernel<<<dim3(BN_ / 32, 3), 128, 0, stream>>>(
        dec_lnb, enc_lnb, wqb, wkb, wvb, bq, bk, bv, Qh, Kh, Vt);

    attn_kernel4<<<dim3(N_ / 64, NH_, B_ * SPLIT_), 256, 0, stream>>>(Qh, Kh, Vt, Op, lpb);

    combine_kernel<<<512, 256, 0, stream>>>(Op, lpb, ctx);

    wo_gemm_kernel<<<BN_ / 32, 256, 0, stream>>>(ctx, wob, bo, dec_lnb, g_out, b_out,
                                                 out1, hbuf);

    ffn1_kernel<<<dim3(BN_ / 32, 4), 128, 0, stream>>>(hbuf, w1b, b1, midb);

    ffn2_kernel<<<BN_ / 32, 256, 0, stream>>>(midb, w2b, b2, out1, out);
}

// Round 6
// 187.679 us; speedup vs baseline: 1.2738x; 1.2738x over previous
//
#include <hip/hip_runtime.h>
#include <hip/hip_bf16.h>
#include <math.h>

#define B_ 2
#define N_ 4096          // H*W*D
#define BN_ 8192
#define NH_ 4
#define SPLIT_ 8         // attention K-split

using bf16x8   = __attribute__((ext_vector_type(8))) __bf16;
using f32x4    = __attribute__((ext_vector_type(4))) float;
using ushortx8 = __attribute__((ext_vector_type(8))) unsigned short;

#if __has_builtin(__builtin_amdgcn_exp2f)
#define FAST_EXP2(x) __builtin_amdgcn_exp2f(x)
#else
#define FAST_EXP2(x) __expf((x) * 0.6931471805599453f)
#endif

static __device__ __forceinline__ unsigned short f2bf(float f) {
    union { __hip_bfloat16 h; unsigned short u; } c;
    c.h = __float2bfloat16(f);
    return c.u;
}
static __device__ __forceinline__ float bf2f(unsigned short u) {
    union { __hip_bfloat16 h; unsigned short u; } c;
    c.u = u;
    return __bfloat162float(c.h);
}
// pack two f32 -> two bf16 (round-biased truncate) in one v_perm_b32
static __device__ __forceinline__ unsigned int pk2bf(float lo, float hi) {
    return __builtin_amdgcn_perm(__float_as_uint(hi) + 0x8000u,
                                 __float_as_uint(lo) + 0x8000u, 0x07060302u);
}

// ---------------------------------------------------------------------------
// Convert all six weight matrices fp32 -> bf16.
// ---------------------------------------------------------------------------
__global__ __launch_bounds__(256)
void convert_weights_kernel(const float* __restrict__ Wq, const float* __restrict__ Wk,
                            const float* __restrict__ Wv, const float* __restrict__ Wo,
                            const float* __restrict__ W1, const float* __restrict__ W2,
                            unsigned short* __restrict__ wq, unsigned short* __restrict__ wk,
                            unsigned short* __restrict__ wv, unsigned short* __restrict__ wo,
                            unsigned short* __restrict__ w1, unsigned short* __restrict__ w2) {
    const int id = blockIdx.x * 256 + threadIdx.x;
    if      (id <  16384) wq[id]          = f2bf(Wq[id]);
    else if (id <  32768) wk[id - 16384]  = f2bf(Wk[id - 16384]);
    else if (id <  49152) wv[id - 32768]  = f2bf(Wv[id - 32768]);
    else if (id <  65536) wo[id - 49152]  = f2bf(Wo[id - 49152]);
    else if (id < 131072) w1[id - 65536]  = f2bf(W1[id - 65536]);
    else                  w2[id - 131072] = f2bf(W2[id - 131072]);
}

// ---------------------------------------------------------------------------
// LayerNorm + transpose (enc & dec merged): fp32 [B,C,N] -> bf16 [B*N, C].
// Grid (N/32, B, 2): z=0 -> enc, z=1 -> dec.
// ---------------------------------------------------------------------------
__global__ __launch_bounds__(256)
void ln_transpose_kernel(const float* __restrict__ enc, const float* __restrict__ dec,
                         const float* __restrict__ g_enc, const float* __restrict__ b_enc,
                         const float* __restrict__ g_dec, const float* __restrict__ b_dec,
                         unsigned short* __restrict__ enc_out,
                         unsigned short* __restrict__ dec_out) {
    __shared__ float tile[128][33];
    __shared__ float mu_s[32], inv_s[32];
    const int z  = blockIdx.z;
    const float* in     = z ? dec   : enc;
    const float* gamma  = z ? g_dec : g_enc;
    const float* beta   = z ? b_dec : b_enc;
    unsigned short* outb = z ? dec_out : enc_out;
    const int b  = blockIdx.y;
    const int n0 = blockIdx.x * 32;
    const int t  = threadIdx.x;
    const float* inb = in + (size_t)b * 128 * N_;

    {
        const int col = t & 31;
        const int r0  = t >> 5;
        for (int j = 0; j < 16; ++j) {
            const int r = r0 + 8 * j;
            tile[r][col] = inb[(size_t)r * N_ + n0 + col];
        }
    }
    __syncthreads();
    {
        const int tok = t >> 3;
        const int ln  = t & 7;
        float s = 0.f, ss = 0.f;
        for (int c = ln; c < 128; c += 8) {
            const float x = tile[c][tok];
            s += x; ss += x * x;
        }
        for (int m = 1; m < 8; m <<= 1) {
            s  += __shfl_xor(s, m);
            ss += __shfl_xor(ss, m);
        }
        if (ln == 0) {
            const float mu  = s * (1.f / 128.f);
            const float var = ss * (1.f / 128.f) - mu * mu;
            mu_s[tok]  = mu;
            inv_s[tok] = rsqrtf(var + 1e-5f);
        }
    }
    __syncthreads();
    const size_t obase = ((size_t)b * N_ + n0) * 128;
    for (int j = 0; j < 16; ++j) {
        const int f  = t + 256 * j;
        const int tk = f >> 7;
        const int c  = f & 127;
        const float x = tile[c][tk];
        outb[obase + f] = f2bf((x - mu_s[tk]) * inv_s[tk] * gamma[c] + beta[c]);
    }
}

// ---------------------------------------------------------------------------
// QKV projection, bf16 MFMA, no LDS. Q is pre-scaled by (1/sqrt(d))*log2(e)
// so attention can use raw exp2. V written pre-transposed [bh, 32, n].
// ---------------------------------------------------------------------------
__global__ __launch_bounds__(128)
void qkv_gemm_kernel(const unsigned short* __restrict__ decb,
                     const unsigned short* __restrict__ encb,
                     const unsigned short* __restrict__ wq,
                     const unsigned short* __restrict__ wk,
                     const unsigned short* __restrict__ wv,
                     const float* __restrict__ bq, const float* __restrict__ bk,
                     const float* __restrict__ bv,
                     unsigned short* __restrict__ Qh, unsigned short* __restrict__ Kh,
                     unsigned short* __restrict__ Vt) {
    const int z = blockIdx.y;
    const int t = threadIdx.x;
    const int wvx = t >> 6, lane = t & 63;
    const int l15 = lane & 15, quad = lane >> 4;
    const int m0 = blockIdx.x * 32 + wvx * 16;
    const unsigned short* X    = (z == 0) ? decb : encb;
    const unsigned short* Wb   = (z == 0) ? wq : (z == 1) ? wk : wv;
    const float*          bias = (z == 0) ? bq : (z == 1) ? bk : bv;

    bf16x8 af[4];
    #pragma unroll
    for (int kk = 0; kk < 4; ++kk)
        af[kk] = *(const bf16x8*)(X + (size_t)(m0 + l15) * 128 + kk * 32 + quad * 8);

    f32x4 acc[8];
    #pragma unroll
    for (int nb = 0; nb < 8; ++nb) {
        f32x4 a = {0.f, 0.f, 0.f, 0.f};
        #pragma unroll
        for (int kk = 0; kk < 4; ++kk) {
            const bf16x8 wf = *(const bf16x8*)(Wb + (size_t)(nb * 16 + l15) * 128 + kk * 32 + quad * 8);
            a = __builtin_amdgcn_mfma_f32_16x16x32_bf16(af[kk], wf, a, 0, 0, 0);
        }
        acc[nb] = a;
    }

    const float qsc = 0.17677669529663687f * 1.4426950408889634f;  // 1/sqrt(32)*log2e
    const int b   = m0 >> 12;
    const int nb0 = (m0 & 4095) + quad * 4;
    #pragma unroll
    for (int nb = 0; nb < 8; ++nb) {
        const int col = nb * 16 + l15;
        const int h = col >> 5, d = col & 31;
        const float bz = bias[col];
        if (z == 2) {
            ushort4 pk;
            pk.x = f2bf(acc[nb][0] + bz);
            pk.y = f2bf(acc[nb][1] + bz);
            pk.z = f2bf(acc[nb][2] + bz);
            pk.w = f2bf(acc[nb][3] + bz);
            *(ushort4*)(Vt + ((size_t)(b * NH_ + h) * 32 + d) * N_ + nb0) = pk;
        } else {
            unsigned short* dst = (z == 0) ? Qh : Kh;
            const float sc = (z == 0) ? qsc : 1.f;
            #pragma unroll
            for (int r = 0; r < 4; ++r) {
                const int n = nb0 + r;
                dst[((size_t)(b * NH_ + h) * N_ + n) * 32 + d] = f2bf((acc[nb][r] + bz) * sc);
            }
        }
    }
}

// ---------------------------------------------------------------------------
// Split-K MFMA flash attention, v5: 64 q per wave (4 Q-frags), 256 q per
// block -> each loaded K/V tile feeds 4x the MFMAs (4x less L2/L3 traffic).
// 1-D grid with XCD-affine ordering: gid = qblk*64 + (s*8+bh); consecutive
// blocks round-robin XCDs, so gid%8 == bh -> each XCD serves exactly one
// (b,h) head; its K+V (512 KB) stays L2-resident.
// Max-free base-2 softmax; K prefetched one chunk ahead; sP wave-private.
// ---------------------------------------------------------------------------
__global__ __launch_bounds__(256)
void attn_kernel5(const unsigned short* __restrict__ Qh,
                  const unsigned short* __restrict__ Kh,
                  const unsigned short* __restrict__ Vt,
                  unsigned short* __restrict__ Op,
                  unsigned short* __restrict__ lp) {
    __shared__ alignas(16) unsigned short sP[4][64][72];  // [wave][q][key], 36.9 KB

    const int gid   = blockIdx.x;
    const int combo = gid & 63;         // s*8 + bh
    const int qblk  = gid >> 6;         // 0..15
    const int bh    = combo & 7;
    const int s     = combo >> 3;
    const int t  = threadIdx.x;
    const int wvx = t >> 6, lane = t & 63;
    const int l15 = lane & 15, quad = lane >> 4;
    const int qw = qblk * 256 + wvx * 64;     // wave's q base (64 rows)
    const size_t hbse = (size_t)bh * N_ * 32;

    // 4 Q fragments (A/B-operand layout: lane l15 -> q, quad*8 -> dims)
    bf16x8 qf[4];
    #pragma unroll
    for (int f = 0; f < 4; ++f)
        qf[f] = *(const bf16x8*)(Qh + hbse + (size_t)(qw + f * 16 + l15) * 32 + quad * 8);

    const unsigned short* Kp = Kh + hbse;
    const unsigned short* Vp = Vt + (size_t)bh * 32 * N_;

    f32x4 o0[4], o1[4];
    float l[4];
    #pragma unroll
    for (int f = 0; f < 4; ++f) {
        o0[f] = f32x4{0.f, 0.f, 0.f, 0.f};
        o1[f] = f32x4{0.f, 0.f, 0.f, 0.f};
        l[f] = 0.f;
    }
    const f32x4 zero = {0.f, 0.f, 0.f, 0.f};

    const int kbeg = s * (N_ / SPLIT_);
    const int kend = kbeg + (N_ / SPLIT_);

    // prefetch first chunk's K tiles
    bf16x8 kf[4];
    #pragma unroll
    for (int c = 0; c < 4; ++c)
        kf[c] = *(const bf16x8*)(Kp + (size_t)(kbeg + c * 16 + l15) * 32 + quad * 8);

    for (int k0 = kbeg; k0 < kend; k0 += 64) {
        // V loads for CURRENT chunk (consumed after the long S^T/exp phase)
        bf16x8 va[2], vb[2];
        #pragma unroll
        for (int s2 = 0; s2 < 2; ++s2) {
            va[s2] = *(const bf16x8*)(Vp + (size_t)l15 * N_        + k0 + s2 * 32 + quad * 8);
            vb[s2] = *(const bf16x8*)(Vp + (size_t)(16 + l15) * N_ + k0 + s2 * 32 + quad * 8);
        }
        // K loads for NEXT chunk
        const int kn = (k0 + 64 < kend) ? (k0 + 64) : kbeg;
        bf16x8 kfn[4];
        #pragma unroll
        for (int c = 0; c < 4; ++c)
            kfn[c] = *(const bf16x8*)(Kp + (size_t)(kn + c * 16 + l15) * 32 + quad * 8);

        // S^T = mfma(K, Q_f) for all 4 q-frags x 4 key-tiles
        #pragma unroll
        for (int f = 0; f < 4; ++f) {
            #pragma unroll
            for (int c = 0; c < 4; ++c) {
                const f32x4 sv = __builtin_amdgcn_mfma_f32_16x16x32_bf16(kf[c], qf[f], zero, 0, 0, 0);
                const float p0 = FAST_EXP2(sv[0]);
                const float p1 = FAST_EXP2(sv[1]);
                const float p2 = FAST_EXP2(sv[2]);
                const float p3 = FAST_EXP2(sv[3]);
                l[f] += (p0 + p1) + (p2 + p3);
                uint2 pk;
                pk.x = pk2bf(p0, p1);
                pk.y = pk2bf(p2, p3);
                *(uint2*)&sP[wvx][f * 16 + l15][c * 16 + quad * 4] = pk;
            }
        }
        // PV: V arrived during S^T phase
        #pragma unroll
        for (int f = 0; f < 4; ++f) {
            #pragma unroll
            for (int s2 = 0; s2 < 2; ++s2) {
                const bf16x8 pf = *(const bf16x8*)&sP[wvx][f * 16 + l15][s2 * 32 + quad * 8];
                o0[f] = __builtin_amdgcn_mfma_f32_16x16x32_bf16(va[s2], pf, o0[f], 0, 0, 0);
                o1[f] = __builtin_amdgcn_mfma_f32_16x16x32_bf16(vb[s2], pf, o1[f], 0, 0, 0);
            }
        }
        #pragma unroll
        for (int c = 0; c < 4; ++c) kf[c] = kfn[c];
    }

    #pragma unroll
    for (int f = 0; f < 4; ++f) {
        float lf = l[f];
        lf += __shfl_xor(lf, 16);
        lf += __shfl_xor(lf, 32);
        const int tok = qw + f * 16 + l15;
        const size_t ob = ((size_t)(s * 8 + bh) * N_ + tok) * 32;
        uint2 w0, w1v;
        w0.x  = pk2bf(o0[f][0], o0[f][1]); w0.y  = pk2bf(o0[f][2], o0[f][3]);
        w1v.x = pk2bf(o1[f][0], o1[f][1]); w1v.y = pk2bf(o1[f][2], o1[f][3]);
        *(uint2*)&Op[ob + quad * 4]      = w0;
        *(uint2*)&Op[ob + 16 + quad * 4] = w1v;
        if (quad == 0)
            lp[(size_t)(s * 8 + bh) * N_ + tok] = f2bf(lf);
    }
}

// ---------------------------------------------------------------------------
// Combine split-K partials: ctx = (sum_s Op)/(sum_s l), bf16 out.
// ---------------------------------------------------------------------------
__global__ __launch_bounds__(256)
void combine_kernel(const unsigned short* __restrict__ Op,
                    const unsigned short* __restrict__ lp,
                    unsigned short* __restrict__ ctx) {
    const int gid = blockIdx.x * 256 + threadIdx.x;   // 0 .. 131071
    const int token = gid >> 4;
    const int c8 = gid & 15;
    const int b = token >> 12, n = token & 4095;
    const int h = c8 >> 2;
    const int d0 = (c8 & 3) * 8;
    const int bh = b * NH_ + h;

    f32x4 sa = {0.f, 0.f, 0.f, 0.f}, sb = {0.f, 0.f, 0.f, 0.f};
    float lt = 0.f;
    #pragma unroll
    for (int s = 0; s < SPLIT_; ++s) {
        const size_t base = ((size_t)(s * 8 + bh) * N_ + n) * 32 + d0;
        const ushortx8 u = *(const ushortx8*)&Op[base];
        sa[0] += bf2f(u[0]); sa[1] += bf2f(u[1]);
        sa[2] += bf2f(u[2]); sa[3] += bf2f(u[3]);
        sb[0] += bf2f(u[4]); sb[1] += bf2f(u[5]);
        sb[2] += bf2f(u[6]); sb[3] += bf2f(u[7]);
        lt += bf2f(lp[(size_t)(s * 8 + bh) * N_ + n]);
    }
    const float inv = 1.f / lt;
    uint4 pk;
    pk.x = pk2bf(sa[0] * inv, sa[1] * inv);
    pk.y = pk2bf(sa[2] * inv, sa[3] * inv);
    pk.z = pk2bf(sb[0] * inv, sb[1] * inv);
    pk.w = pk2bf(sb[2] * inv, sb[3] * inv);
    *(uint4*)(ctx + (size_t)token * 128 + c8 * 8) = pk;
}

// ---------------------------------------------------------------------------
// Wo projection + residual + fused full-row LayerNorm. 4 waves/block:
// 2 token-tiles x 2 K-halves; LDS reduce; kh==0 waves run the epilogue.
// ---------------------------------------------------------------------------
__global__ __launch_bounds__(256)
void wo_gemm_kernel(const unsigned short* __restrict__ ctx,
                    const unsigned short* __restrict__ wo,
                    const float* __restrict__ bo,
                    const unsigned short* __restrict__ decb,
                    const float* __restrict__ g, const float* __restrict__ be,
                    unsigned short* __restrict__ out1,
                    unsigned short* __restrict__ hb) {
    __shared__ alignas(16) float sred[2][64][32];   // 16 KB
    const int t = threadIdx.x;
    const int wvx = t >> 6, lane = t & 63;
    const int pair = wvx >> 1, kh = wvx & 1;
    const int l15 = lane & 15, quad = lane >> 4;
    const int m0 = blockIdx.x * 32 + pair * 16;

    bf16x8 af[2];
    #pragma unroll
    for (int kk = 0; kk < 2; ++kk)
        af[kk] = *(const bf16x8*)(ctx + (size_t)(m0 + l15) * 128 + (kh * 2 + kk) * 32 + quad * 8);

    float v[8][4];
    #pragma unroll
    for (int nb = 0; nb < 8; ++nb) {
        f32x4 a = {0.f, 0.f, 0.f, 0.f};
        #pragma unroll
        for (int kk = 0; kk < 2; ++kk) {
            const bf16x8 wf = *(const bf16x8*)(wo + (size_t)(nb * 16 + l15) * 128 + (kh * 2 + kk) * 32 + quad * 8);
            a = __builtin_amdgcn_mfma_f32_16x16x32_bf16(af[kk], wf, a, 0, 0, 0);
        }
        #pragma unroll
        for (int r = 0; r < 4; ++r) v[nb][r] = a[r];
    }

    if (kh == 1) {
        #pragma unroll
        for (int nb = 0; nb < 8; ++nb)
            *(f32x4*)&sred[pair][lane][nb * 4] = *(f32x4*)&v[nb][0];
    }
    __syncthreads();
    if (kh == 0) {
        #pragma unroll
        for (int nb = 0; nb < 8; ++nb) {
            const f32x4 p = *(const f32x4*)&sred[pair][lane][nb * 4];
            const int col = nb * 16 + l15;
            const float bz = bo[col];
            #pragma unroll
            for (int r = 0; r < 4; ++r) {
                const int tok = m0 + quad * 4 + r;
                v[nb][r] += p[r] + bz + bf2f(decb[(size_t)tok * 128 + col]);
            }
        }
        float mu[4], inv[4];
        #pragma unroll
        for (int r = 0; r < 4; ++r) {
            float s = 0.f, ss = 0.f;
            #pragma unroll
            for (int nb = 0; nb < 8; ++nb) { s += v[nb][r]; ss += v[nb][r] * v[nb][r]; }
            for (int m = 1; m < 16; m <<= 1) {
                s  += __shfl_xor(s, m);
                ss += __shfl_xor(ss, m);
            }
            mu[r] = s * (1.f / 128.f);
            inv[r] = rsqrtf(ss * (1.f / 128.f) - mu[r] * mu[r] + 1e-5f);
        }
        #pragma unroll
        for (int nb = 0; nb < 8; ++nb) {
            const int col = nb * 16 + l15;
            const float gg = g[col], bb2 = be[col];
            #pragma unroll
            for (int r = 0; r < 4; ++r) {
                const int tok = m0 + quad * 4 + r;
                out1[(size_t)tok * 128 + col] = f2bf(v[nb][r]);
                hb[(size_t)tok * 128 + col]   = f2bf((v[nb][r] - mu[r]) * inv[r] * gg + bb2);
            }
        }
    }
}

// ---------------------------------------------------------------------------
// FFN1: mid = gelu(hb @ W1^T + b1), bf16 [BN, 512]. Grid (BN/32, 4).
// ---------------------------------------------------------------------------
__global__ __launch_bounds__(128)
void ffn1_kernel(const unsigned short* __restrict__ hb,
                 const unsigned short* __restrict__ w1,
                 const float* __restrict__ b1,
                 unsigned short* __restrict__ midb) {
    const int t = threadIdx.x;
    const int wvx = t >> 6, lane = t & 63;
    const int l15 = lane & 15, quad = lane >> 4;
    const int m0 = blockIdx.x * 32 + wvx * 16;
    const int nbase = blockIdx.y * 128;

    bf16x8 af[4];
    #pragma unroll
    for (int kk = 0; kk < 4; ++kk)
        af[kk] = *(const bf16x8*)(hb + (size_t)(m0 + l15) * 128 + kk * 32 + quad * 8);

    #pragma unroll
    for (int nb = 0; nb < 8; ++nb) {
        f32x4 a = {0.f, 0.f, 0.f, 0.f};
        const int col = nbase + nb * 16 + l15;
        #pragma unroll
        for (int kk = 0; kk < 4; ++kk) {
            const bf16x8 wf = *(const bf16x8*)(w1 + (size_t)col * 128 + kk * 32 + quad * 8);
            a = __builtin_amdgcn_mfma_f32_16x16x32_bf16(af[kk], wf, a, 0, 0, 0);
        }
        const float bz = b1[col];
        #pragma unroll
        for (int r = 0; r < 4; ++r) {
            const int tok = m0 + quad * 4 + r;
            float x = a[r] + bz;
            x = 0.5f * x * (1.f + erff(x * 0.70710678118f));
            midb[(size_t)tok * 512 + col] = f2bf(x);
        }
    }
}

// ---------------------------------------------------------------------------
// FFN2: final = mid @ W2^T + b2 + out1 -> [B,128,N] fp32. 4 waves/block:
// 2 token-tiles x 2 K-halves (K=512); LDS reduce; kh==0 epilogue.
// ---------------------------------------------------------------------------
__global__ __launch_bounds__(256)
void ffn2_kernel(const unsigned short* __restrict__ midb,
                 const unsigned short* __restrict__ w2,
                 const float* __restrict__ b2,
                 const unsigned short* __restrict__ out1,
                 float* __restrict__ out) {
    __shared__ alignas(16) float sred[2][64][32];   // 16 KB
    const int t = threadIdx.x;
    const int wvx = t >> 6, lane = t & 63;
    const int pair = wvx >> 1, kh = wvx & 1;
    const int l15 = lane & 15, quad = lane >> 4;
    const int m0 = blockIdx.x * 32 + pair * 16;

    bf16x8 af[8];
    #pragma unroll
    for (int kk = 0; kk < 8; ++kk)
        af[kk] = *(const bf16x8*)(midb + (size_t)(m0 + l15) * 512 + (kh * 8 + kk) * 32 + quad * 8);

    float v[8][4];
    #pragma unroll
    for (int nb = 0; nb < 8; ++nb) {
        f32x4 a = {0.f, 0.f, 0.f, 0.f};
        const int col = nb * 16 + l15;
        #pragma unroll
        for (int kk = 0; kk < 8; ++kk) {
            const bf16x8 wf = *(const bf16x8*)(w2 + (size_t)col * 512 + (kh * 8 + kk) * 32 + quad * 8);
            a = __builtin_amdgcn_mfma_f32_16x16x32_bf16(af[kk], wf, a, 0, 0, 0);
        }
        #pragma unroll
        for (int r = 0; r < 4; ++r) v[nb][r] = a[r];
    }

    if (kh == 1) {
        #pragma unroll
        for (int nb = 0; nb < 8; ++nb)
            *(f32x4*)&sred[pair][lane][nb * 4] = *(f32x4*)&v[nb][0];
    }
    __syncthreads();
    if (kh == 0) {
        const int b = m0 >> 12;
        const int nb0 = (m0 & 4095) + quad * 4;
        #pragma unroll
        for (int nb = 0; nb < 8; ++nb) {
            const f32x4 p = *(const f32x4*)&sred[pair][lane][nb * 4];
            const int col = nb * 16 + l15;
            const float bz = b2[col];
            f32x4 res;
            #pragma unroll
            for (int r = 0; r < 4; ++r) {
                const int tok = m0 + quad * 4 + r;
                res[r] = v[nb][r] + p[r] + bz + bf2f(out1[(size_t)tok * 128 + col]);
            }
            *(f32x4*)&out[((size_t)(b * 128 + col)) * N_ + nb0] = res;
        }
    }
}

// ---------------------------------------------------------------------------
extern "C" void kernel_launch(void* const* d_in, const int* in_sizes, int n_in,
                              void* d_out, int out_size, void* d_ws, size_t ws_size,
                              hipStream_t stream) {
    const float* enc   = (const float*)d_in[0];
    const float* dec   = (const float*)d_in[1];
    const float* Wq    = (const float*)d_in[2];
    const float* bq    = (const float*)d_in[3];
    const float* Wk    = (const float*)d_in[4];
    const float* bk    = (const float*)d_in[5];
    const float* Wv    = (const float*)d_in[6];
    const float* bv    = (const float*)d_in[7];
    const float* Wo    = (const float*)d_in[8];
    const float* bo    = (const float*)d_in[9];
    const float* g_enc = (const float*)d_in[10];
    const float* b_enc = (const float*)d_in[11];
    const float* g_dec = (const float*)d_in[12];
    const float* b_dec = (const float*)d_in[13];
    const float* g_out = (const float*)d_in[14];
    const float* b_out = (const float*)d_in[15];
    const float* W1    = (const float*)d_in[16];
    const float* b1    = (const float*)d_in[17];
    const float* W2    = (const float*)d_in[18];
    const float* b2    = (const float*)d_in[19];
    float* out = (float*)d_out;
    char*  W   = (char*)d_ws;

    // workspace layout (same 27 MB footprint as R3-R5 which passed)
    unsigned short* wqb = (unsigned short*)(W);
    unsigned short* wkb = wqb + 16384;
    unsigned short* wvb = wkb + 16384;
    unsigned short* wob = wvb + 16384;
    unsigned short* w1b = wob + 16384;
    unsigned short* w2b = w1b + 65536;                                  // ends 384 KB
    unsigned short* enc_lnb = (unsigned short*)(W + (512ull  << 10));   // [0.5, 2.5) MB
    unsigned short* dec_lnb = (unsigned short*)(W + (2560ull << 10));   // [2.5, 4.5)
    unsigned short* Qh      = (unsigned short*)(W + (4608ull << 10));   // [4.5, 6.5)
    unsigned short* Kh      = (unsigned short*)(W + (6656ull << 10));   // [6.5, 8.5)
    unsigned short* Vt      = (unsigned short*)(W + (8704ull << 10));   // [8.5, 10.5)
    unsigned short* Op      = (unsigned short*)(W + (10752ull << 10));  // 16 MB (SPLIT=8)
    unsigned short* lpb     = (unsigned short*)(W + (27136ull << 10));  // [26.5, 27)
    unsigned short* ctx  = enc_lnb;                 // overlay (enc dead after QKV)
    unsigned short* out1 = Qh;                      // overlay (Q dead after attn)
    unsigned short* hbuf = Kh;                      // overlay (K dead after attn)
    unsigned short* midb = Op;                      // overlay (Op dead after combine)

    convert_weights_kernel<<<768, 256, 0, stream>>>(Wq, Wk, Wv, Wo, W1, W2,
                                                    wqb, wkb, wvb, wob, w1b, w2b);

    ln_transpose_kernel<<<dim3(N_ / 32, B_, 2), 256, 0, stream>>>(
        enc, dec, g_enc, b_enc, g_dec, b_dec, enc_lnb, dec_lnb);

    qkv_gemm_kernel<<<dim3(BN_ / 32, 3), 128, 0, stream>>>(
        dec_lnb, enc_lnb, wqb, wkb, wvb, bq, bk, bv, Qh, Kh, Vt);

    // 1024 blocks, XCD-affine: gid = qblk*64 + (s*8+bh) -> gid%8 == bh
    attn_kernel5<<<1024, 256, 0, stream>>>(Qh, Kh, Vt, Op, lpb);

    combine_kernel<<<512, 256, 0, stream>>>(Op, lpb, ctx);

    wo_gemm_kernel<<<BN_ / 32, 256, 0, stream>>>(ctx, wob, bo, dec_lnb, g_out, b_out,
                                                 out1, hbuf);

    ffn1_kernel<<<dim3(BN_ / 32, 4), 128, 0, stream>>>(hbuf, w1b, b1, midb);

    ffn2_kernel<<<BN_ / 32, 256, 0, stream>>>(midb, w2b, b2, out1, out);
}